// Round 3
// baseline (347.828 us; speedup 1.0000x reference)
//
#include <hip/hip_runtime.h>
#include <hip/hip_bf16.h>

#define B_ 4
#define L_ 4096
#define D_ 1024
#define H_ 2048
#define M_ (B_*L_)          // 16384 rows
#define NCHUNK 64
#define TCHUNK 64           // NCHUNK*TCHUNK == L_

typedef __attribute__((ext_vector_type(8))) short short8;
typedef __attribute__((ext_vector_type(4))) float floatx4;

__device__ __forceinline__ ushort f2bf(float f){
  uint u = __float_as_uint(f);
  u += 0x7FFFu + ((u >> 16) & 1u);          // RNE
  return (ushort)(u >> 16);
}
__device__ __forceinline__ float bf2f(ushort s){
  return __uint_as_float(((uint)s) << 16);
}

// ---------------- converts ----------------
__global__ void cvt_f32_bf16(const float4* __restrict__ in, ushort4* __restrict__ out, int n4){
  int i = blockIdx.x * blockDim.x + threadIdx.x;
  int stride = gridDim.x * blockDim.x;
  for (; i < n4; i += stride){
    float4 v = in[i];
    ushort4 o;
    o.x = f2bf(v.x); o.y = f2bf(v.y); o.z = f2bf(v.z); o.w = f2bf(v.w);
    out[i] = o;
  }
}

// in [R][C] f32 -> out [orow(C)][R] bf16  (R,C multiples of 32)
// mode 0: orow = c; mode 1: orow = 32*(c/16)+(c%16); mode 2: +16 (i-slot)
__global__ void transpose_cvt(const float* __restrict__ in, ushort* __restrict__ out,
                              int R, int C, int mode){
  __shared__ float tile[32][33];
  int c0 = blockIdx.x * 32, r0 = blockIdx.y * 32;
  int tx = threadIdx.x, ty = threadIdx.y;   // (32,8)
  #pragma unroll
  for (int i = 0; i < 4; i++){
    int r = r0 + ty + i*8;
    tile[ty + i*8][tx] = in[(size_t)r*C + c0 + tx];
  }
  __syncthreads();
  #pragma unroll
  for (int i = 0; i < 4; i++){
    int c = c0 + ty + i*8;
    int orow = (mode == 0) ? c : (((c >> 4) << 5) + ((mode == 2) ? 16 : 0) + (c & 15));
    out[(size_t)orow*R + r0 + tx] = f2bf(tile[tx][ty + i*8]);
  }
}

// ---------------- 256x256 8-phase GEMM ----------------
template<int Q, int QN>
__device__ __forceinline__ void mfma16(floatx4 (&acc)[8][4], const short8 (&ar)[4][2], const short8 (&br)[2][2]){
  #pragma unroll
  for (int i = 0; i < 4; i++)
    #pragma unroll
    for (int j = 0; j < 2; j++)
      #pragma unroll
      for (int kk = 0; kk < 2; kk++)
        acc[Q*4+i][QN*2+j] = __builtin_amdgcn_mfma_f32_16x16x32_bf16(ar[i][kk], br[j][kk], acc[Q*4+i][QN*2+j], 0, 0, 0);
}

template<int Q>
__device__ __forceinline__ void ldAq(short8 (&ar)[4][2], const ushort* Ab, int wm, int l15, int l4){
  #pragma unroll
  for (int i = 0; i < 4; i++){
    int row = wm*128 + (Q*4+i)*16 + l15;
    #pragma unroll
    for (int kk = 0; kk < 2; kk++){
      int c = kk*4 + l4;
      ar[i][kk] = *(const short8*)(Ab + row*64 + ((c ^ (row & 7)) * 8));
    }
  }
}

template<int QN>
__device__ __forceinline__ void ldBq(short8 (&br)[2][2], const ushort* Bb, int wn, int l15, int l4){
  #pragma unroll
  for (int j = 0; j < 2; j++){
    int row = wn*64 + QN*32 + j*16 + l15;
    #pragma unroll
    for (int kk = 0; kk < 2; kk++){
      int c = kk*4 + l4;
      br[j][kk] = *(const short8*)(Bb + row*64 + ((c ^ (row & 7)) * 8));
    }
  }
}

// STAGE: half 0=A-q0, 1=A-q1, 2=B-qn0, 3=B-qn1. Source tile clamped, dest buffer NOT.
#define STAGE(KT, HALF) do { \
  const int ktd_ = (KT) & 1; \
  const int kts_ = ((KT) < NT) ? (KT) : (NT-1); \
  const ushort* src_ = ((HALF) < 2) ? A : Bm; \
  const int t0_ = ((HALF) < 2) ? tm : tn; \
  ushort* dst_ = (((HALF) < 2) ? AsB : BsB) + ktd_ * 16384; \
  _Pragma("unroll") \
  for (int iss_ = 0; iss_ < 2; iss_++){ \
    int idx_ = iss_*512 + tid; \
    int rl_  = idx_ >> 3; \
    int row_ = ((HALF) < 2) ? ((rl_ & 63) + (((HALF)&1) << 6) + ((rl_ >> 6) << 7)) \
                            : ((rl_ & 31) + (((HALF)&1) << 5) + ((rl_ >> 5) << 6)); \
    int c_   = idx_ & 7; \
    __builtin_amdgcn_global_load_lds( \
      (const __attribute__((address_space(1))) void*)(src_ + (size_t)(t0_ + row_)*K + kts_*64 + ((c_ ^ (row_ & 7)) * 8)), \
      (__attribute__((address_space(3))) void*)(dst_ + row_*64 + c_*8), 16, 0, 0); \
  } \
} while(0)

#define PH_PRE() do { \
  __builtin_amdgcn_s_barrier(); \
  asm volatile("s_waitcnt lgkmcnt(0)" ::: "memory"); \
  __builtin_amdgcn_sched_barrier(0); \
  __builtin_amdgcn_s_setprio(1); \
} while(0)

#define PH_POST() do { \
  __builtin_amdgcn_s_setprio(0); \
  __builtin_amdgcn_s_barrier(); \
} while(0)

// A [M][K] bf16 row-major; Bm [N][K] bf16 (B^T). EPI 0: y=acc+b0 (f32, stride D_).
// EPI 1: interleaved f/i pairs -> packed (r,z) bf16x2 into rz (stride H_).
template<int K, int EPI>
__global__ __launch_bounds__(512, 2) void gemm256(
    const ushort* __restrict__ A,
    const ushort* __restrict__ Bm,
    const float*  __restrict__ b0,
    const float*  __restrict__ b1,
    void*         __restrict__ outp)
{
  constexpr int NT = K / 64;
  extern __shared__ ushort smem[];
  ushort* AsB = smem;            // 2 bufs x 256x64
  ushort* BsB = smem + 32768;

  const int tid  = threadIdx.x;
  const int lane = tid & 63;
  const int wid  = tid >> 6;
  const int wm = wid >> 2, wn = wid & 3;
  const int l15 = lane & 15;
  const int l4  = lane >> 4;

  const int nwg = gridDim.x;
  const int bid = blockIdx.x;
  const int swz = (bid & 7) * (nwg >> 3) + (bid >> 3);   // nwg % 8 == 0
  const int bm = swz & 63;                               // NBM = 64 for both gemms
  const int bn = swz >> 6;
  const int tm = bm << 8;
  const int tn = bn << 8;

  floatx4 acc[8][4];
  #pragma unroll
  for (int m = 0; m < 8; m++)
    #pragma unroll
    for (int n = 0; n < 4; n++) acc[m][n] = (floatx4)(0.f);

  short8 ar[4][2], br[2][2];

  // prologue: tile0 {A0,B1,A1,B0}, tile1 {A0,B1,A1}; B0(1) staged in-loop at t=0 ph1
  STAGE(0, 0); STAGE(0, 3); STAGE(0, 1); STAGE(0, 2);
  STAGE(1, 0); STAGE(1, 3); STAGE(1, 1);
  asm volatile("s_waitcnt vmcnt(6)" ::: "memory");   // tile0's 8 loads landed
  __builtin_amdgcn_s_barrier();

  for (int t = 0; t < NT; ++t){
    const ushort* Ab = AsB + (t & 1) * 16384;
    const ushort* Bb = BsB + (t & 1) * 16384;
    // phase 1: quadrant (0,0); A0,B0 die (reads -> regs)
    ldAq<0>(ar, Ab, wm, l15, l4);
    ldBq<0>(br, Bb, wn, l15, l4);
    STAGE(t+1, 2);                  // B0(t+1) -> other buffer (dead since (t-1):ph4)
    PH_PRE();
    mfma16<0,0>(acc, ar, br);
    PH_POST();
    // phase 2: (0,1); reuse A0 regs, read B1
    ldBq<1>(br, Bb, wn, l15, l4);
    STAGE(t+2, 0);                  // A0(t+2) -> this buffer (died ph1)
    PH_PRE();
    mfma16<0,1>(acc, ar, br);
    PH_POST();
    // phase 3: (1,1); read A1, reuse B1 regs
    ldAq<1>(ar, Ab, wm, l15, l4);
    STAGE(t+2, 3);                  // B1(t+2) (died ph2)
    PH_PRE();
    mfma16<1,1>(acc, ar, br);
    PH_POST();
    // phase 4: (1,0); re-read B0, reuse A1 regs
    ldBq<0>(br, Bb, wn, l15, l4);
    STAGE(t+2, 1);                  // A1(t+2) (died ph3)
    PH_PRE();
    mfma16<1,0>(acc, ar, br);
    __builtin_amdgcn_s_setprio(0);
    asm volatile("s_waitcnt vmcnt(6)" ::: "memory");  // tile t+1 fully landed
    __builtin_amdgcn_s_barrier();
  }
  asm volatile("s_waitcnt vmcnt(0)" ::: "memory");

  if (EPI == 0){
    float* y = (float*)outp;
    #pragma unroll
    for (int nf = 0; nf < 4; nf++){
      int col = tn + wn*64 + nf*16 + l15;
      float bv = b0[col];
      #pragma unroll
      for (int mf = 0; mf < 8; mf++){
        int row0 = tm + wm*128 + mf*16 + l4*4;
        #pragma unroll
        for (int r = 0; r < 4; r++)
          y[(size_t)(row0 + r)*D_ + col] = acc[mf][nf][r] + bv;
      }
    }
  } else {
    uint* rz = (uint*)outp;
    #pragma unroll
    for (int p = 0; p < 2; p++){
      int nf = p*2;
      int h = ((tn + wn*64 + nf*16) >> 1) + l15;
      float bfc = b0[h], bic = b1[h];
      float lin = (float)h * (1.0f / (float)(H_-1));
      #pragma unroll
      for (int mf = 0; mf < 8; mf++){
        int row0 = tm + wm*128 + mf*16 + l4*4;
        #pragma unroll
        for (int r = 0; r < 4; r++){
          float pf = acc[mf][nf][r]   + bfc;
          float pi = acc[mf][nf+1][r] + bic;
          float rem = lin / (1.0f + __expf(-pf));
          float z   = rem * tanhf(pi);
          rz[(size_t)(row0 + r)*H_ + h] = (uint)f2bf(rem) | ((uint)f2bf(z) << 16);
        }
      }
    }
  }
}

// ---------------- scan ----------------
__global__ void scan_passA(const uint* __restrict__ rz, float* __restrict__ Ac, float* __restrict__ Bc){
  int gidx = blockIdx.x * blockDim.x + threadIdx.x;
  int h = gidx & (H_-1);
  int t2 = gidx >> 11;
  int chunk = t2 & (NCHUNK-1);
  int b = t2 >> 6;
  const uint* p = rz + ((size_t)(b*L_ + chunk*TCHUNK))*H_ + h;
  float A = 1.f, Bv = 0.f;
  #pragma unroll 8
  for (int t = 0; t < TCHUNK; t++){
    uint u = p[(size_t)t*H_];
    float r = bf2f((ushort)(u & 0xFFFFu));
    float z = bf2f((ushort)(u >> 16));
    float a = 1.f - r;
    A *= a;
    Bv = fmaf(a, Bv, z);
  }
  size_t o = ((size_t)(b*NCHUNK + chunk))*H_ + h;
  Ac[o] = A; Bc[o] = Bv;
}

__global__ void scan_passB(const float* __restrict__ Ac, const float* __restrict__ Bc,
                           const float* __restrict__ hidden, float* __restrict__ hst,
                           float* __restrict__ hlast){
  int idx = blockIdx.x * blockDim.x + threadIdx.x;  // B_*H_ threads
  int h = idx & (H_-1);
  int b = idx >> 11;
  float run = hidden[idx];
  for (int c = 0; c < NCHUNK; c++){
    size_t o = ((size_t)(b*NCHUNK + c))*H_ + h;
    hst[o] = run;
    run = fmaf(Ac[o], run, Bc[o]);
  }
  hlast[idx] = run;
}

__global__ void scan_passC(const uint* __restrict__ rz, const float* __restrict__ hst,
                           ushort* __restrict__ hb){
  int gidx = blockIdx.x * blockDim.x + threadIdx.x;
  int h = gidx & (H_-1);
  int t2 = gidx >> 11;
  int chunk = t2 & (NCHUNK-1);
  int b = t2 >> 6;
  float hv = hst[((size_t)(b*NCHUNK + chunk))*H_ + h];
  const uint* p = rz + ((size_t)(b*L_ + chunk*TCHUNK))*H_ + h;
  ushort*   q  = hb + ((size_t)(b*L_ + chunk*TCHUNK))*H_ + h;
  #pragma unroll 8
  for (int t = 0; t < TCHUNK; t++){
    uint u = p[(size_t)t*H_];
    float r = bf2f((ushort)(u & 0xFFFFu));
    float z = bf2f((ushort)(u >> 16));
    hv = fmaf(1.f - r, hv, z);
    q[(size_t)t*H_] = f2bf(hv);
  }
}

extern "C" void kernel_launch(void* const* d_in, const int* in_sizes, int n_in,
                              void* d_out, int out_size, void* d_ws, size_t ws_size,
                              hipStream_t stream)
{
  const float* x      = (const float*)d_in[0];
  const float* hidden = (const float*)d_in[1];
  const float* Wf     = (const float*)d_in[2];
  const float* bf     = (const float*)d_in[3];
  const float* Wi     = (const float*)d_in[4];
  const float* bi     = (const float*)d_in[5];
  const float* Wo     = (const float*)d_in[6];
  const float* bo     = (const float*)d_in[7];

  float* y     = (float*)d_out;                 // [M_][D_]
  float* hlast = y + (size_t)M_*D_;             // [B_][H_]

  char* ws = (char*)d_ws;
  ushort* xb   = (ushort*)ws;  ws += (size_t)M_*D_*2;
  ushort* WfiT = (ushort*)ws;  ws += (size_t)(2*H_)*D_*2;   // [4096][1024] interleaved
  ushort* WoT  = (ushort*)ws;  ws += (size_t)D_*H_*2;
  uint*   rz   = (uint*)ws;    ws += (size_t)M_*H_*4;
  ushort* hb   = (ushort*)ws;  ws += (size_t)M_*H_*2;
  float*  Ac   = (float*)ws;   ws += (size_t)B_*NCHUNK*H_*4;
  float*  Bc   = (float*)ws;   ws += (size_t)B_*NCHUNK*H_*4;
  float*  hst  = (float*)ws;   ws += (size_t)B_*NCHUNK*H_*4;

  (void)hipFuncSetAttribute((const void*)&gemm256<D_, 1>,
      hipFuncAttributeMaxDynamicSharedMemorySize, 128*1024);
  (void)hipFuncSetAttribute((const void*)&gemm256<H_, 0>,
      hipFuncAttributeMaxDynamicSharedMemorySize, 128*1024);

  cvt_f32_bf16<<<2048, 256, 0, stream>>>((const float4*)x, (ushort4*)xb, (M_*D_)/4);
  transpose_cvt<<<dim3(H_/32, D_/32), dim3(32,8), 0, stream>>>(Wf, WfiT, D_, H_, 1);
  transpose_cvt<<<dim3(H_/32, D_/32), dim3(32,8), 0, stream>>>(Wi, WfiT, D_, H_, 2);
  transpose_cvt<<<dim3(D_/32, H_/32), dim3(32,8), 0, stream>>>(Wo, WoT, H_, D_, 0);

  // gemm1: [16384][1024] @ [4096][1024]^T -> rz (64x16 tiles = 1024 blocks)
  gemm256<D_, 1><<<64*16, 512, 128*1024, stream>>>(xb, WfiT, bf, bi, rz);

  scan_passA<<<B_*NCHUNK*(H_/256), 256, 0, stream>>>(rz, Ac, Bc);
  scan_passB<<<(B_*H_)/256, 256, 0, stream>>>(Ac, Bc, hidden, hst, hlast);
  scan_passC<<<B_*NCHUNK*(H_/256), 256, 0, stream>>>(rz, hst, hb);

  // gemm2: [16384][2048] @ [1024][2048]^T -> y (64x4 tiles = 256 blocks)
  gemm256<H_, 0><<<64*4, 512, 128*1024, stream>>>(hb, WoT, bo, nullptr, y);
}

// Round 4
// 337.389 us; speedup vs baseline: 1.0309x; 1.0309x over previous
//
#include <hip/hip_runtime.h>
#include <hip/hip_bf16.h>

#define B_ 4
#define L_ 4096
#define D_ 1024
#define H_ 2048
#define M_ (B_*L_)          // 16384 rows
#define NCHUNK 64
#define TCHUNK 64           // NCHUNK*TCHUNK == L_

typedef __attribute__((ext_vector_type(8))) short short8;
typedef __attribute__((ext_vector_type(4))) float floatx4;

__device__ __forceinline__ ushort f2bf(float f){
  uint u = __float_as_uint(f);
  u += 0x7FFFu + ((u >> 16) & 1u);          // RNE
  return (ushort)(u >> 16);
}
__device__ __forceinline__ float bf2f(ushort s){
  return __uint_as_float(((uint)s) << 16);
}

// ---------------- converts ----------------
__global__ void cvt_f32_bf16(const float4* __restrict__ in, ushort4* __restrict__ out, int n4){
  int i = blockIdx.x * blockDim.x + threadIdx.x;
  int stride = gridDim.x * blockDim.x;
  for (; i < n4; i += stride){
    float4 v = in[i];
    ushort4 o;
    o.x = f2bf(v.x); o.y = f2bf(v.y); o.z = f2bf(v.z); o.w = f2bf(v.w);
    out[i] = o;
  }
}

// in [R][C] f32 -> out [orow(C)][R] bf16  (R,C multiples of 32)
// mode 0: orow = c; mode 1: orow = 32*(c/16)+(c%16); mode 2: +16 (i-slot)
__global__ void transpose_cvt(const float* __restrict__ in, ushort* __restrict__ out,
                              int R, int C, int mode){
  __shared__ float tile[32][33];
  int c0 = blockIdx.x * 32, r0 = blockIdx.y * 32;
  int tx = threadIdx.x, ty = threadIdx.y;   // (32,8)
  #pragma unroll
  for (int i = 0; i < 4; i++){
    int r = r0 + ty + i*8;
    tile[ty + i*8][tx] = in[(size_t)r*C + c0 + tx];
  }
  __syncthreads();
  #pragma unroll
  for (int i = 0; i < 4; i++){
    int c = c0 + ty + i*8;
    int orow = (mode == 0) ? c : (((c >> 4) << 5) + ((mode == 2) ? 16 : 0) + (c & 15));
    out[(size_t)orow*R + r0 + tx] = f2bf(tile[tx][ty + i*8]);
  }
}

// ---------------- 256x256 8-phase GEMM ----------------
template<int Q, int QN>
__device__ __forceinline__ void mfma16(floatx4 (&acc)[8][4], const short8 (&ar)[4][2], const short8 (&br)[2][2]){
  #pragma unroll
  for (int i = 0; i < 4; i++)
    #pragma unroll
    for (int j = 0; j < 2; j++)
      #pragma unroll
      for (int kk = 0; kk < 2; kk++)
        acc[Q*4+i][QN*2+j] = __builtin_amdgcn_mfma_f32_16x16x32_bf16(ar[i][kk], br[j][kk], acc[Q*4+i][QN*2+j], 0, 0, 0);
}

template<int Q>
__device__ __forceinline__ void ldAq(short8 (&ar)[4][2], const ushort* Ab, int wm, int l15, int l4){
  #pragma unroll
  for (int i = 0; i < 4; i++){
    int row = wm*128 + (Q*4+i)*16 + l15;
    #pragma unroll
    for (int kk = 0; kk < 2; kk++){
      int c = kk*4 + l4;
      ar[i][kk] = *(const short8*)(Ab + row*64 + ((c ^ (row & 7)) * 8));
    }
  }
}

template<int QN>
__device__ __forceinline__ void ldBq(short8 (&br)[2][2], const ushort* Bb, int wn, int l15, int l4){
  #pragma unroll
  for (int j = 0; j < 2; j++){
    int row = wn*64 + QN*32 + j*16 + l15;
    #pragma unroll
    for (int kk = 0; kk < 2; kk++){
      int c = kk*4 + l4;
      br[j][kk] = *(const short8*)(Bb + row*64 + ((c ^ (row & 7)) * 8));
    }
  }
}

// STAGE: half 0=A-q0, 1=A-q1, 2=B-qn0, 3=B-qn1. Source tile clamped, dest buffer NOT.
#define STAGE(KT, HALF) do { \
  const int ktd_ = (KT) & 1; \
  const int kts_ = ((KT) < NT) ? (KT) : (NT-1); \
  const ushort* src_ = ((HALF) < 2) ? A : Bm; \
  const int t0_ = ((HALF) < 2) ? tm : tn; \
  ushort* dst_ = (((HALF) < 2) ? AsB : BsB) + ktd_ * 16384; \
  _Pragma("unroll") \
  for (int iss_ = 0; iss_ < 2; iss_++){ \
    int idx_ = iss_*512 + tid; \
    int rl_  = idx_ >> 3; \
    int row_ = ((HALF) < 2) ? ((rl_ & 63) + (((HALF)&1) << 6) + ((rl_ >> 6) << 7)) \
                            : ((rl_ & 31) + (((HALF)&1) << 5) + ((rl_ >> 5) << 6)); \
    int c_   = idx_ & 7; \
    __builtin_amdgcn_global_load_lds( \
      (const __attribute__((address_space(1))) void*)(src_ + (size_t)(t0_ + row_)*K + kts_*64 + ((c_ ^ (row_ & 7)) * 8)), \
      (__attribute__((address_space(3))) void*)(dst_ + row_*64 + c_*8), 16, 0, 0); \
  } \
} while(0)

#define PH_PRE() do { \
  __builtin_amdgcn_s_barrier(); \
  asm volatile("s_waitcnt lgkmcnt(0)" ::: "memory"); \
  __builtin_amdgcn_s_setprio(1); \
} while(0)

#define PH_POST() do { \
  __builtin_amdgcn_s_setprio(0); \
  __builtin_amdgcn_s_barrier(); \
} while(0)

// A [M][K] bf16 row-major; Bm [N][K] bf16 (B^T). EPI 0: y=acc+b0 (f32, stride D_).
// EPI 1: interleaved f/i pairs -> packed (r,z) bf16x2 into rz (stride H_).
// Grid: 64 m-tiles x NBN n-tiles; per-XCD chunk -> 4x4 patches (L2-resident panels).
template<int K, int NBN, int EPI>
__global__ __launch_bounds__(512, 2) void gemm256(
    const ushort* __restrict__ A,
    const ushort* __restrict__ Bm,
    const float*  __restrict__ b0,
    const float*  __restrict__ b1,
    void*         __restrict__ outp)
{
  constexpr int NT = K / 64;
  constexpr int PN = NBN / 4;      // patches along n per chunk
  extern __shared__ ushort smem[];
  ushort* AsB = smem;              // 2 bufs x 256x64
  ushort* BsB = smem + 32768;

  const int tid  = threadIdx.x;
  const int lane = tid & 63;
  const int wid  = tid >> 6;
  const int wm = wid >> 2, wn = wid & 3;
  const int l15 = lane & 15;
  const int l4  = lane >> 4;

  // patch mapping: concurrent blocks on an XCD share a 4x4 tile patch
  const int bid   = blockIdx.x;
  const int xcd   = bid & 7;
  const int local = bid >> 3;
  const int P = local >> 4;
  const int w = local & 15;
  const int pm = P / PN, pn = P % PN;
  const int bm = xcd * 8 + pm * 4 + (w >> 2);
  const int bn = pn * 4 + (w & 3);
  const int tm = bm << 8;
  const int tn = bn << 8;

  floatx4 acc[8][4];
  #pragma unroll
  for (int m = 0; m < 8; m++)
    #pragma unroll
    for (int n = 0; n < 4; n++) acc[m][n] = (floatx4)(0.f);

  short8 ar[4][2], br[2][2];

  // prologue: tile0 {A0,B1,A1,B0}, tile1 {A0,B1,A1}; B0(1) staged in-loop at t=0 ph1
  STAGE(0, 0); STAGE(0, 3); STAGE(0, 1); STAGE(0, 2);
  STAGE(1, 0); STAGE(1, 3); STAGE(1, 1);
  asm volatile("s_waitcnt vmcnt(6)" ::: "memory");   // tile0's 8 loads landed
  __builtin_amdgcn_s_barrier();

  for (int t = 0; t < NT; ++t){
    const ushort* Ab = AsB + (t & 1) * 16384;
    const ushort* Bb = BsB + (t & 1) * 16384;
    // phase 1: quadrant (0,0); A0,B0 -> regs
    ldAq<0>(ar, Ab, wm, l15, l4);
    ldBq<0>(br, Bb, wn, l15, l4);
    STAGE(t+1, 2);                  // B0(t+1) -> other buffer (dead since (t-1):ph4)
    PH_PRE();
    mfma16<0,0>(acc, ar, br);
    PH_POST();
    // phase 2: (0,1); reuse A0 regs, read B1
    ldBq<1>(br, Bb, wn, l15, l4);
    STAGE(t+2, 0);                  // A0(t+2) -> this buffer (died ph1)
    PH_PRE();
    mfma16<0,1>(acc, ar, br);
    PH_POST();
    // phase 3: (1,1); read A1, reuse B1 regs
    ldAq<1>(ar, Ab, wm, l15, l4);
    STAGE(t+2, 3);                  // B1(t+2) (died ph2)
    PH_PRE();
    mfma16<1,1>(acc, ar, br);
    PH_POST();
    // phase 4: (1,0); re-read B0, reuse A1 regs
    ldBq<0>(br, Bb, wn, l15, l4);
    STAGE(t+2, 1);                  // A1(t+2) (died ph3)
    PH_PRE();
    mfma16<1,0>(acc, ar, br);
    __builtin_amdgcn_s_setprio(0);
    asm volatile("s_waitcnt vmcnt(6)" ::: "memory");  // tile t+1 fully landed
    __builtin_amdgcn_s_barrier();
  }
  asm volatile("s_waitcnt vmcnt(0)" ::: "memory");

  if (EPI == 0){
    float* y = (float*)outp;
    #pragma unroll
    for (int nf = 0; nf < 4; nf++){
      int col = tn + wn*64 + nf*16 + l15;
      float bv = b0[col];
      #pragma unroll
      for (int mf = 0; mf < 8; mf++){
        int row0 = tm + wm*128 + mf*16 + l4*4;
        #pragma unroll
        for (int r = 0; r < 4; r++)
          y[(size_t)(row0 + r)*D_ + col] = acc[mf][nf][r] + bv;
      }
    }
  } else {
    uint* rz = (uint*)outp;
    #pragma unroll
    for (int p = 0; p < 2; p++){
      int nf = p*2;
      int h = ((tn + wn*64 + nf*16) >> 1) + l15;
      float bfc = b0[h], bic = b1[h];
      float lin = (float)h * (1.0f / (float)(H_-1));
      #pragma unroll
      for (int mf = 0; mf < 8; mf++){
        int row0 = tm + wm*128 + mf*16 + l4*4;
        #pragma unroll
        for (int r = 0; r < 4; r++){
          float pf = acc[mf][nf][r]   + bfc;
          float pi = acc[mf][nf+1][r] + bic;
          float rem = lin / (1.0f + __expf(-pf));
          float z   = rem * tanhf(pi);
          rz[(size_t)(row0 + r)*H_ + h] = (uint)f2bf(rem) | ((uint)f2bf(z) << 16);
        }
      }
    }
  }
}

// ---------------- scan ----------------
__global__ void scan_passA(const uint* __restrict__ rz, float* __restrict__ Ac, float* __restrict__ Bc){
  int gidx = blockIdx.x * blockDim.x + threadIdx.x;
  int h = gidx & (H_-1);
  int t2 = gidx >> 11;
  int chunk = t2 & (NCHUNK-1);
  int b = t2 >> 6;
  const uint* p = rz + ((size_t)(b*L_ + chunk*TCHUNK))*H_ + h;
  float A = 1.f, Bv = 0.f;
  #pragma unroll 8
  for (int t = 0; t < TCHUNK; t++){
    uint u = p[(size_t)t*H_];
    float r = bf2f((ushort)(u & 0xFFFFu));
    float z = bf2f((ushort)(u >> 16));
    float a = 1.f - r;
    A *= a;
    Bv = fmaf(a, Bv, z);
  }
  size_t o = ((size_t)(b*NCHUNK + chunk))*H_ + h;
  Ac[o] = A; Bc[o] = Bv;
}

__global__ void scan_passB(const float* __restrict__ Ac, const float* __restrict__ Bc,
                           const float* __restrict__ hidden, float* __restrict__ hst,
                           float* __restrict__ hlast){
  int idx = blockIdx.x * blockDim.x + threadIdx.x;  // B_*H_ threads
  int h = idx & (H_-1);
  int b = idx >> 11;
  float run = hidden[idx];
  for (int c = 0; c < NCHUNK; c++){
    size_t o = ((size_t)(b*NCHUNK + c))*H_ + h;
    hst[o] = run;
    run = fmaf(Ac[o], run, Bc[o]);
  }
  hlast[idx] = run;
}

__global__ void scan_passC(const uint* __restrict__ rz, const float* __restrict__ hst,
                           ushort* __restrict__ hb){
  int gidx = blockIdx.x * blockDim.x + threadIdx.x;
  int h = gidx & (H_-1);
  int t2 = gidx >> 11;
  int chunk = t2 & (NCHUNK-1);
  int b = t2 >> 6;
  float hv = hst[((size_t)(b*NCHUNK + chunk))*H_ + h];
  const uint* p = rz + ((size_t)(b*L_ + chunk*TCHUNK))*H_ + h;
  ushort*   q  = hb + ((size_t)(b*L_ + chunk*TCHUNK))*H_ + h;
  #pragma unroll 8
  for (int t = 0; t < TCHUNK; t++){
    uint u = p[(size_t)t*H_];
    float r = bf2f((ushort)(u & 0xFFFFu));
    float z = bf2f((ushort)(u >> 16));
    hv = fmaf(1.f - r, hv, z);
    q[(size_t)t*H_] = f2bf(hv);
  }
}

extern "C" void kernel_launch(void* const* d_in, const int* in_sizes, int n_in,
                              void* d_out, int out_size, void* d_ws, size_t ws_size,
                              hipStream_t stream)
{
  const float* x      = (const float*)d_in[0];
  const float* hidden = (const float*)d_in[1];
  const float* Wf     = (const float*)d_in[2];
  const float* bf     = (const float*)d_in[3];
  const float* Wi     = (const float*)d_in[4];
  const float* bi     = (const float*)d_in[5];
  const float* Wo     = (const float*)d_in[6];
  const float* bo     = (const float*)d_in[7];

  float* y     = (float*)d_out;                 // [M_][D_]
  float* hlast = y + (size_t)M_*D_;             // [B_][H_]

  char* ws = (char*)d_ws;
  ushort* xb   = (ushort*)ws;  ws += (size_t)M_*D_*2;
  ushort* WfiT = (ushort*)ws;  ws += (size_t)(2*H_)*D_*2;   // [4096][1024] interleaved
  ushort* WoT  = (ushort*)ws;  ws += (size_t)D_*H_*2;
  uint*   rz   = (uint*)ws;    ws += (size_t)M_*H_*4;
  ushort* hb   = (ushort*)ws;  ws += (size_t)M_*H_*2;
  float*  Ac   = (float*)ws;   ws += (size_t)B_*NCHUNK*H_*4;
  float*  Bc   = (float*)ws;   ws += (size_t)B_*NCHUNK*H_*4;
  float*  hst  = (float*)ws;   ws += (size_t)B_*NCHUNK*H_*4;

  (void)hipFuncSetAttribute((const void*)&gemm256<D_, 16, 1>,
      hipFuncAttributeMaxDynamicSharedMemorySize, 128*1024);
  (void)hipFuncSetAttribute((const void*)&gemm256<H_, 4, 0>,
      hipFuncAttributeMaxDynamicSharedMemorySize, 128*1024);

  cvt_f32_bf16<<<2048, 256, 0, stream>>>((const float4*)x, (ushort4*)xb, (M_*D_)/4);
  transpose_cvt<<<dim3(H_/32, D_/32), dim3(32,8), 0, stream>>>(Wf, WfiT, D_, H_, 1);
  transpose_cvt<<<dim3(H_/32, D_/32), dim3(32,8), 0, stream>>>(Wi, WfiT, D_, H_, 2);
  transpose_cvt<<<dim3(D_/32, H_/32), dim3(32,8), 0, stream>>>(Wo, WoT, H_, D_, 0);

  // gemm1: [16384][1024] @ [4096][1024]^T -> rz (64x16 tiles = 1024 blocks)
  gemm256<D_, 16, 1><<<64*16, 512, 128*1024, stream>>>(xb, WfiT, bf, bi, rz);

  scan_passA<<<B_*NCHUNK*(H_/256), 256, 0, stream>>>(rz, Ac, Bc);
  scan_passB<<<(B_*H_)/256, 256, 0, stream>>>(Ac, Bc, hidden, hst, hlast);
  scan_passC<<<B_*NCHUNK*(H_/256), 256, 0, stream>>>(rz, hst, hb);

  // gemm2: [16384][2048] @ [1024][2048]^T -> y (64x4 tiles = 256 blocks)
  gemm256<H_, 4, 0><<<64*4, 512, 128*1024, stream>>>(hb, WoT, bo, nullptr, y);
}

// Round 5
// 305.506 us; speedup vs baseline: 1.1385x; 1.1044x over previous
//
#include <hip/hip_runtime.h>
#include <hip/hip_bf16.h>

#define B_ 4
#define L_ 4096
#define D_ 1024
#define H_ 2048
#define M_ (B_*L_)          // 16384 rows
#define NCHUNK 64
#define TCHUNK 64           // NCHUNK*TCHUNK == L_

typedef __attribute__((ext_vector_type(8))) short short8;
typedef __attribute__((ext_vector_type(4))) float floatx4;

__device__ __forceinline__ ushort f2bf(float f){
  uint u = __float_as_uint(f);
  u += 0x7FFFu + ((u >> 16) & 1u);          // RNE
  return (ushort)(u >> 16);
}
__device__ __forceinline__ float bf2f(ushort s){
  return __uint_as_float(((uint)s) << 16);
}

// ---------------- converts ----------------
__global__ void cvt_f32_bf16(const float4* __restrict__ in, ushort4* __restrict__ out, int n4){
  int i = blockIdx.x * blockDim.x + threadIdx.x;
  int stride = gridDim.x * blockDim.x;
  for (; i < n4; i += stride){
    float4 v = in[i];
    ushort4 o;
    o.x = f2bf(v.x); o.y = f2bf(v.y); o.z = f2bf(v.z); o.w = f2bf(v.w);
    out[i] = o;
  }
}

// in [R][C] f32 -> out [orow(C)][R] bf16  (R,C multiples of 32)
// mode 0: orow = c; mode 1: orow = 32*(c/16)+(c%16); mode 2: +16 (i-slot)
__global__ void transpose_cvt(const float* __restrict__ in, ushort* __restrict__ out,
                              int R, int C, int mode){
  __shared__ float tile[32][33];
  int c0 = blockIdx.x * 32, r0 = blockIdx.y * 32;
  int tx = threadIdx.x, ty = threadIdx.y;   // (32,8)
  #pragma unroll
  for (int i = 0; i < 4; i++){
    int r = r0 + ty + i*8;
    tile[ty + i*8][tx] = in[(size_t)r*C + c0 + tx];
  }
  __syncthreads();
  #pragma unroll
  for (int i = 0; i < 4; i++){
    int c = c0 + ty + i*8;
    int orow = (mode == 0) ? c : (((c >> 4) << 5) + ((mode == 2) ? 16 : 0) + (c & 15));
    out[(size_t)orow*R + r0 + tx] = f2bf(tile[tx][ty + i*8]);
  }
}

// ---------------- unified GEMM (m97 structure + chunk XOR swizzle) ----------------
// A [M][K] bf16 row-major; Bm [N][K] bf16 (B^T layout)
// EPI 0: out = float* y, y = acc + b0[col]
// EPI 1: out = uint* rz (packed r,z bf16x2) + per-chunk scan summaries Ac,Bc
// Block mapping: XCD-chunked 4x4 patches (each XCD gets a 16-mtile stripe; a
// patch's 4 A-panels + 4 B-panels ~2MB = L2-resident).
template<int K, int N, int NBN, int EPI>
__global__ __launch_bounds__(256, 4) void gemm_bt(
    const ushort* __restrict__ A,
    const ushort* __restrict__ Bm,
    const float*  __restrict__ b0,
    const float*  __restrict__ b1,
    void*         __restrict__ outp,
    float*        __restrict__ Ac,
    float*        __restrict__ Bc)
{
  __shared__ ushort As[128*64];
  __shared__ ushort Bs[128*64];

  const int tid  = threadIdx.x;
  const int lane = tid & 63;
  const int wid  = tid >> 6;
  const int wr = wid >> 1, wc = wid & 1;
  const int l15 = lane & 15;
  const int l4  = lane >> 4;

  // XCD patch mapping (bijective: 8 xcds x (16/4 x NBN/4 patches) x 16 blocks)
  constexpr int PN = NBN / 4;
  const int bid   = blockIdx.x;
  const int xcd   = bid & 7;
  const int local = bid >> 3;
  const int P = local >> 4;
  const int w = local & 15;
  const int pm = P / PN, pn = P % PN;
  const int bm = xcd*16 + pm*4 + (w >> 2);
  const int bn = pn*4 + (w & 3);
  const int tm = bm * 128;
  const int tn = bn * 128;

  floatx4 acc[4][4];
  #pragma unroll
  for (int m = 0; m < 4; m++)
    #pragma unroll
    for (int n = 0; n < 4; n++) acc[m][n] = (floatx4)(0.f);

  for (int k0 = 0; k0 < K; k0 += 64){
    const ushort* Ab = A  + (size_t)tm*K + k0;
    const ushort* Bb = Bm + (size_t)tn*K + k0;
    #pragma unroll
    for (int i = 0; i < 4; i++){
      int idx = i*256 + tid;                    // 16B chunk id, 1024 chunks = 16KB
      int row = idx >> 3;                       // 8 chunks per 128B row
      int ce  = (((idx & 7) ^ (row & 7)) * 8);  // swizzled source element offset
      __builtin_amdgcn_global_load_lds((const __attribute__((address_space(1))) void*)(Ab + (size_t)row*K + ce),
                                       (__attribute__((address_space(3))) void*)(As + idx*8), 16, 0, 0);
      __builtin_amdgcn_global_load_lds((const __attribute__((address_space(1))) void*)(Bb + (size_t)row*K + ce),
                                       (__attribute__((address_space(3))) void*)(Bs + idx*8), 16, 0, 0);
    }
    __syncthreads();
    #pragma unroll
    for (int kk = 0; kk < 64; kk += 32){
      short8 af[4], bf_[4];
      #pragma unroll
      for (int m = 0; m < 4; m++){
        int row = wr*64 + m*16 + l15;
        int c   = (kk >> 3) + l4;               // chunk 0..7
        af[m] = *(const short8*)(As + row*64 + ((c ^ (row & 7)) * 8));
      }
      #pragma unroll
      for (int n = 0; n < 4; n++){
        int row = wc*64 + n*16 + l15;
        int c   = (kk >> 3) + l4;
        bf_[n] = *(const short8*)(Bs + row*64 + ((c ^ (row & 7)) * 8));
      }
      #pragma unroll
      for (int m = 0; m < 4; m++)
        #pragma unroll
        for (int n = 0; n < 4; n++)
          acc[m][n] = __builtin_amdgcn_mfma_f32_16x16x32_bf16(af[m], bf_[n], acc[m][n], 0, 0, 0);
    }
    __syncthreads();
  }

  if (EPI == 0){
    float* y = (float*)outp;
    #pragma unroll
    for (int n = 0; n < 4; n++){
      int col = tn + wc*64 + n*16 + l15;
      float bv = b0[col];
      #pragma unroll
      for (int m = 0; m < 4; m++){
        int row0 = tm + wr*64 + m*16 + l4*4;
        #pragma unroll
        for (int r = 0; r < 4; r++)
          y[(size_t)(row0 + r)*N + col] = acc[m][n][r] + bv;
      }
    }
  } else {
    // interleaved cols: frag n (even) = f-preact, frag n+1 = i-preact, same h set.
    // Also compute this wave's 64-t chunk scan summary (A=prod a, B) per h.
    uint* rz = (uint*)outp;
    const int rowbase = tm + wr*64;             // wave's chunk start (global M row)
    const int bidx  = rowbase >> 12;            // / L_
    const int chunk = (rowbase >> 6) & (NCHUNK-1);
    #pragma unroll
    for (int p = 0; p < 2; p++){
      int n = p*2;
      int h = ((tn + wc*64 + n*16) >> 1) + l15;
      float bfc = b0[h], bic = b1[h];
      float lin = (float)h * (1.0f / (float)(H_-1));
      float Am = 1.f, Bmv = 0.f;                // running chunk composition (t-order)
      #pragma unroll
      for (int m = 0; m < 4; m++){
        int row0 = tm + wr*64 + m*16 + l4*4;
        float As_ = 1.f, Bs_ = 0.f;             // thread-local 4-t segment
        #pragma unroll
        for (int r = 0; r < 4; r++){
          float pf = acc[m][n][r]   + bfc;
          float pi = acc[m][n+1][r] + bic;
          float rem = lin / (1.0f + __expf(-pf));
          float z   = rem * tanhf(pi);
          rz[(size_t)(row0 + r)*H_ + h] = (uint)f2bf(rem) | ((uint)f2bf(z) << 16);
          float a = 1.f - rem;
          As_ *= a;
          Bs_ = fmaf(a, Bs_, z);
        }
        // butterfly across l4 (lane bits 4,5), order-aware (non-commutative)
        #pragma unroll
        for (int s = 16; s <= 32; s <<= 1){
          float Ao = __shfl_xor(As_, s, 64);
          float Bo = __shfl_xor(Bs_, s, 64);
          if (lane & s){ Bs_ = fmaf(As_, Bo, Bs_); }   // partner earlier
          else         { Bs_ = fmaf(Ao, Bs_, Bo); }    // mine earlier
          As_ *= Ao;
        }
        // append segment m
        Bmv = fmaf(As_, Bmv, Bs_);
        Am  *= As_;
      }
      if ((lane & 48) == 0){                    // l4 == 0: one writer per h
        size_t o = ((size_t)(bidx*NCHUNK + chunk))*H_ + h;
        Ac[o] = Am; Bc[o] = Bmv;
      }
    }
  }
}

// ---------------- scan ----------------
__global__ void scan_passB(const float* __restrict__ Ac, const float* __restrict__ Bc,
                           const float* __restrict__ hidden, float* __restrict__ hst,
                           float* __restrict__ hlast){
  int idx = blockIdx.x * blockDim.x + threadIdx.x;  // B_*H_ threads
  int h = idx & (H_-1);
  int b = idx >> 11;
  float run = hidden[idx];
  for (int c = 0; c < NCHUNK; c++){
    size_t o = ((size_t)(b*NCHUNK + c))*H_ + h;
    hst[o] = run;
    run = fmaf(Ac[o], run, Bc[o]);
  }
  hlast[idx] = run;
}

__global__ void scan_passC(const uint* __restrict__ rz, const float* __restrict__ hst,
                           ushort* __restrict__ hb){
  int gidx = blockIdx.x * blockDim.x + threadIdx.x;
  int h = gidx & (H_-1);
  int t2 = gidx >> 11;
  int chunk = t2 & (NCHUNK-1);
  int b = t2 >> 6;
  float hv = hst[((size_t)(b*NCHUNK + chunk))*H_ + h];
  const uint* p = rz + ((size_t)(b*L_ + chunk*TCHUNK))*H_ + h;
  ushort*   q  = hb + ((size_t)(b*L_ + chunk*TCHUNK))*H_ + h;
  #pragma unroll 8
  for (int t = 0; t < TCHUNK; t++){
    uint u = p[(size_t)t*H_];
    float r = bf2f((ushort)(u & 0xFFFFu));
    float z = bf2f((ushort)(u >> 16));
    hv = fmaf(1.f - r, hv, z);
    q[(size_t)t*H_] = f2bf(hv);
  }
}

extern "C" void kernel_launch(void* const* d_in, const int* in_sizes, int n_in,
                              void* d_out, int out_size, void* d_ws, size_t ws_size,
                              hipStream_t stream)
{
  const float* x      = (const float*)d_in[0];
  const float* hidden = (const float*)d_in[1];
  const float* Wf     = (const float*)d_in[2];
  const float* bf     = (const float*)d_in[3];
  const float* Wi     = (const float*)d_in[4];
  const float* bi     = (const float*)d_in[5];
  const float* Wo     = (const float*)d_in[6];
  const float* bo     = (const float*)d_in[7];

  float* y     = (float*)d_out;                 // [M_][D_]
  float* hlast = y + (size_t)M_*D_;             // [B_][H_]

  char* ws = (char*)d_ws;
  ushort* xb   = (ushort*)ws;  ws += (size_t)M_*D_*2;
  ushort* WfiT = (ushort*)ws;  ws += (size_t)(2*H_)*D_*2;   // [4096][1024] interleaved
  ushort* WoT  = (ushort*)ws;  ws += (size_t)D_*H_*2;
  uint*   rz   = (uint*)ws;    ws += (size_t)M_*H_*4;
  ushort* hb   = (ushort*)ws;  ws += (size_t)M_*H_*2;
  float*  Ac   = (float*)ws;   ws += (size_t)B_*NCHUNK*H_*4;
  float*  Bc   = (float*)ws;   ws += (size_t)B_*NCHUNK*H_*4;
  float*  hst  = (float*)ws;   ws += (size_t)B_*NCHUNK*H_*4;

  cvt_f32_bf16<<<2048, 256, 0, stream>>>((const float4*)x, (ushort4*)xb, (M_*D_)/4);
  transpose_cvt<<<dim3(H_/32, D_/32), dim3(32,8), 0, stream>>>(Wf, WfiT, D_, H_, 1);
  transpose_cvt<<<dim3(H_/32, D_/32), dim3(32,8), 0, stream>>>(Wi, WfiT, D_, H_, 2);
  transpose_cvt<<<dim3(D_/32, H_/32), dim3(32,8), 0, stream>>>(Wo, WoT, H_, D_, 0);

  // gemm1: [16384][1024] @ [4096][1024]^T -> rz + chunk summaries (4096 blocks)
  gemm_bt<D_, 2*H_, 32, 1><<<4096, 256, 0, stream>>>(xb, WfiT, bf, bi, rz, Ac, Bc);

  scan_passB<<<(B_*H_)/256, 256, 0, stream>>>(Ac, Bc, hidden, hst, hlast);
  scan_passC<<<B_*NCHUNK*(H_/256), 256, 0, stream>>>(rz, hst, hb);

  // gemm2: [16384][2048] @ [1024][2048]^T -> y (1024 blocks)
  gemm_bt<H_, D_, 8, 0><<<1024, 256, 0, stream>>>(hb, WoT, bo, nullptr, y, nullptr, nullptr);
}